// Round 1
// baseline (1665.112 us; speedup 1.0000x reference)
//
#include <hip/hip_runtime.h>
#include <hip/hip_bf16.h>
#include <cstddef>

typedef __attribute__((ext_vector_type(8))) short s16x8;
typedef __attribute__((ext_vector_type(4))) short s16x4;
typedef __attribute__((ext_vector_type(4))) float f32x4;

#define MFMA_BF16(a, b, c) __builtin_amdgcn_mfma_f32_16x16x32_bf16((a), (b), (c), 0, 0, 0)

__device__ __forceinline__ short f2bf(float f) {
    union { float f; unsigned u; } cv; cv.f = f;
    unsigned u = cv.u;
    unsigned r = (u + 0x7FFFu + ((u >> 16) & 1u)) >> 16;  // RNE
    return (short)r;
}

// ---------------------------------------------------------------------------
// NT GEMM: C[m][n] = sum_k A[m][k] * B[n][k] + bias, K=1024.
// MODE 0: A=x[32768,1024],  B=Wk[1024,1024], bias per col, C bf16 ld=1024 (k_ws)
// MODE 1: A=Wv[1024,1024],  B=x_b[4096,1024] (batch=blockIdx.z), bias per row,
//         C bf16 ld=4096 (vT_ws, batch-offset)  -> stores V transposed for free
// MODE 2: A=pairmean(x)[16384,1024], B=Wq, bias per col, C f32 ld=1024 (q out)
// ---------------------------------------------------------------------------
template <int MODE>
__global__ __launch_bounds__(256, 2) void gemm_nt(
    const float* __restrict__ Ap, const float* __restrict__ Bp,
    const float* __restrict__ bias, void* __restrict__ Cp)
{
    __shared__ short As[128 * 64];
    __shared__ short Bs[128 * 64];
    const int tid = threadIdx.x;
    const int bx = blockIdx.x, by = blockIdx.y;
    const int w = tid >> 6, l = tid & 63, l15 = l & 15, lhi = l >> 4;
    const int wy = w >> 1, wx = w & 1;
    const int X = (l15 & 7) << 3;  // frag-read swizzle (rowframe &7 == l15&7)

    const float* Bmat = Bp + (MODE == 1 ? (size_t)blockIdx.z * (size_t)(4096 * 1024) : 0);

    f32x4 acc[4][4];
    #pragma unroll
    for (int m = 0; m < 4; ++m)
        #pragma unroll
        for (int n = 0; n < 4; ++n) acc[m][n] = (f32x4){0.f, 0.f, 0.f, 0.f};

    const int kcs = tid & 15, r0 = tid >> 4;

    for (int kt = 0; kt < 16; ++kt) {
        const int k0 = kt * 64 + kcs * 4;
        #pragma unroll
        for (int p = 0; p < 8; ++p) {
            const int r = r0 + p * 16;
            const int e = (kcs * 4) ^ ((r & 7) << 3);
            float ax, ay, az, aw;
            if (MODE == 2) {
                const float* s0 = Ap + (size_t)(by * 128 + r) * 2048 + k0;
                float4 u0 = *(const float4*)s0;
                float4 u1 = *(const float4*)(s0 + 1024);
                ax = 0.5f * (u0.x + u1.x); ay = 0.5f * (u0.y + u1.y);
                az = 0.5f * (u0.z + u1.z); aw = 0.5f * (u0.w + u1.w);
            } else {
                float4 u = *(const float4*)(Ap + (size_t)(by * 128 + r) * 1024 + k0);
                ax = u.x; ay = u.y; az = u.z; aw = u.w;
            }
            s16x4 sa = { f2bf(ax), f2bf(ay), f2bf(az), f2bf(aw) };
            *(s16x4*)&As[r * 64 + e] = sa;
            float4 ub = *(const float4*)(Bmat + (size_t)(bx * 128 + r) * 1024 + k0);
            s16x4 sb = { f2bf(ub.x), f2bf(ub.y), f2bf(ub.z), f2bf(ub.w) };
            *(s16x4*)&Bs[r * 64 + e] = sb;
        }
        __syncthreads();
        #pragma unroll
        for (int kk = 0; kk < 2; ++kk) {
            const int e = (kk * 32 + lhi * 8) ^ X;
            s16x8 af[4], bf[4];
            #pragma unroll
            for (int m = 0; m < 4; ++m)
                af[m] = *(const s16x8*)&As[(wy * 64 + m * 16 + l15) * 64 + e];
            #pragma unroll
            for (int n = 0; n < 4; ++n)
                bf[n] = *(const s16x8*)&Bs[(wx * 64 + n * 16 + l15) * 64 + e];
            #pragma unroll
            for (int m = 0; m < 4; ++m)
                #pragma unroll
                for (int n = 0; n < 4; ++n)
                    acc[m][n] = MFMA_BF16(af[m], bf[n], acc[m][n]);
        }
        __syncthreads();
    }

    const size_t zoff = (MODE == 1) ? (size_t)blockIdx.z * (size_t)(1024 * 4096) : 0;
    #pragma unroll
    for (int m = 0; m < 4; ++m) {
        #pragma unroll
        for (int j = 0; j < 4; ++j) {
            const int row = by * 128 + wy * 64 + m * 16 + lhi * 4 + j;
            const float brow = (MODE == 1) ? bias[row] : 0.f;
            #pragma unroll
            for (int n = 0; n < 4; ++n) {
                const int col = bx * 128 + wx * 64 + n * 16 + l15;
                float v = acc[m][n][j] + ((MODE == 1) ? brow : bias[col]);
                if (MODE == 0)      ((short*)Cp)[(size_t)row * 1024 + col] = f2bf(v);
                else if (MODE == 1) ((short*)Cp)[zoff + (size_t)row * 4096 + col] = f2bf(v);
                else                ((float*)Cp)[(size_t)row * 1024 + col] = v;
            }
        }
    }
}

// ---------------------------------------------------------------------------
// Flash attention: per block: batch b = blockIdx&7 (batch<->XCD affinity),
// 64 q-rows, loop kv in tiles of 128. 8 waves; wave w owns S cols w*16..+16
// and O cols w*128..+128. Q (scaled 1/32) staged once in swizzled LDS.
// K read from k_ws[kv][d] (bf16), V read from vT_ws[d][kv] (bf16).
// ---------------------------------------------------------------------------
__global__ __launch_bounds__(512, 2) void flash_attn(
    const float* __restrict__ qf, const short* __restrict__ kws,
    const short* __restrict__ vT, float* __restrict__ out1,
    float* __restrict__ out2)
{
    __shared__ short Qs[64 * 1024];   // 128 KB
    __shared__ short Ps[64 * 128];    // 16 KB
    __shared__ float red[8 * 64];
    __shared__ float m_lds[64];
    __shared__ float l_lds[64];
    __shared__ float scl_lds[64];

    const int tid = threadIdx.x;
    const int b = blockIdx.x & 7;
    const int q0 = (blockIdx.x >> 3) * 64;
    const int w = tid >> 6, l = tid & 63, l15 = l & 15, lhi = l >> 4;
    const int X = (l15 & 7) << 3;

    // stage Q tile (fp32 -> bf16, fold in SCALE = 1/32)
    {
        const int r = tid >> 3, c8 = tid & 7;
        const float4* qrow = (const float4*)(qf + (size_t)(b * 2048 + q0 + r) * 1024);
        #pragma unroll 4
        for (int p = 0; p < 32; ++p) {
            const int chunk = c8 + p * 8;
            float4 v = qrow[chunk];
            s16x4 sv = { f2bf(v.x * 0.03125f), f2bf(v.y * 0.03125f),
                         f2bf(v.z * 0.03125f), f2bf(v.w * 0.03125f) };
            *(s16x4*)&Qs[r * 1024 + ((chunk * 4) ^ ((r & 7) << 3))] = sv;
        }
    }
    if (tid < 64) { m_lds[tid] = -1e30f; l_lds[tid] = 0.f; }
    __syncthreads();

    f32x4 o[4][8];
    #pragma unroll
    for (int m = 0; m < 4; ++m)
        #pragma unroll
        for (int n = 0; n < 8; ++n) o[m][n] = (f32x4){0.f, 0.f, 0.f, 0.f};

    for (int kt = 0; kt < 32; ++kt) {
        // --- S_w[64,16] = Q @ K_tile^T (wave w covers kv rows w*16..+16)
        f32x4 s[4];
        #pragma unroll
        for (int m = 0; m < 4; ++m) s[m] = (f32x4){0.f, 0.f, 0.f, 0.f};
        const short* kb = kws + (size_t)(b * 4096 + kt * 128 + w * 16 + l15) * 1024 + lhi * 8;
        #pragma unroll 4
        for (int ks = 0; ks < 32; ++ks) {
            const s16x8 bfr = *(const s16x8*)(kb + ks * 32);
            const int e = (ks * 32 + lhi * 8) ^ X;
            #pragma unroll
            for (int m = 0; m < 4; ++m) {
                const s16x8 afr = *(const s16x8*)&Qs[(m * 16 + l15) * 1024 + e];
                s[m] = MFMA_BF16(afr, bfr, s[m]);
            }
        }
        // --- per-row max of this wave's 16 cols, to LDS
        float mx[4][4];
        #pragma unroll
        for (int m = 0; m < 4; ++m)
            #pragma unroll
            for (int j = 0; j < 4; ++j) {
                float v = s[m][j];
                v = fmaxf(v, __shfl_xor(v, 1));
                v = fmaxf(v, __shfl_xor(v, 2));
                v = fmaxf(v, __shfl_xor(v, 4));
                v = fmaxf(v, __shfl_xor(v, 8));
                mx[m][j] = v;
            }
        if (l15 == 0) {
            #pragma unroll
            for (int m = 0; m < 4; ++m)
                #pragma unroll
                for (int j = 0; j < 4; ++j)
                    red[w * 64 + m * 16 + lhi * 4 + j] = mx[m][j];
        }
        __syncthreads();  // (1)
        if (tid < 64) {
            float mt = red[tid];
            #pragma unroll
            for (int w2 = 1; w2 < 8; ++w2) mt = fmaxf(mt, red[w2 * 64 + tid]);
            const float mo = m_lds[tid];
            const float mn = fmaxf(mo, mt);
            scl_lds[tid] = __expf(mo - mn);
            m_lds[tid] = mn;
        }
        __syncthreads();  // (2)
        // --- P = exp(S - m_new): write bf16 P, row-sums, rescale O
        float rs[4][4];
        #pragma unroll
        for (int m = 0; m < 4; ++m) {
            #pragma unroll
            for (int j = 0; j < 4; ++j) {
                const int row = m * 16 + lhi * 4 + j;
                const float p = __expf(s[m][j] - m_lds[row]);
                Ps[row * 128 + ((w * 16 + l15) ^ ((row & 7) << 3))] = f2bf(p);
                float v = p;
                v += __shfl_xor(v, 1);
                v += __shfl_xor(v, 2);
                v += __shfl_xor(v, 4);
                v += __shfl_xor(v, 8);
                rs[m][j] = v;
                const float sc = scl_lds[row];
                #pragma unroll
                for (int n = 0; n < 8; ++n) o[m][n][j] *= sc;
            }
        }
        if (l15 == 0) {
            #pragma unroll
            for (int m = 0; m < 4; ++m)
                #pragma unroll
                for (int j = 0; j < 4; ++j)
                    red[w * 64 + m * 16 + lhi * 4 + j] = rs[m][j];
        }
        __syncthreads();  // (3)
        if (tid < 64) {
            float ssum = red[tid];
            #pragma unroll
            for (int w2 = 1; w2 < 8; ++w2) ssum += red[w2 * 64 + tid];
            l_lds[tid] = l_lds[tid] * scl_lds[tid] + ssum;
        }
        // --- O_w[64,128] += P[64,128] @ V_tile (B from vT: rows=d, K-contig)
        const short* vbase = vT + ((size_t)b * 1024 + w * 128 + l15) * 4096
                             + (size_t)kt * 128 + lhi * 8;
        #pragma unroll
        for (int kk = 0; kk < 4; ++kk) {
            const int e = (kk * 32 + lhi * 8) ^ X;
            s16x8 af[4];
            #pragma unroll
            for (int m = 0; m < 4; ++m)
                af[m] = *(const s16x8*)&Ps[(m * 16 + l15) * 128 + e];
            #pragma unroll
            for (int n = 0; n < 8; ++n) {
                const s16x8 bfr = *(const s16x8*)(vbase + (size_t)(n * 16) * 4096 + kk * 32);
                #pragma unroll
                for (int m = 0; m < 4; ++m)
                    o[m][n] = MFMA_BF16(af[m], bfr, o[m][n]);
            }
        }
        __syncthreads();  // (4) protects red/Ps for next tile & l_lds final
    }

    // epilogue: normalize by l, write k_out twice
    #pragma unroll
    for (int m = 0; m < 4; ++m) {
        #pragma unroll
        for (int j = 0; j < 4; ++j) {
            const int lrow = m * 16 + lhi * 4 + j;
            const float inv = 1.0f / l_lds[lrow];
            const size_t grow = (size_t)(b * 2048 + q0 + lrow) * 1024;
            #pragma unroll
            for (int n = 0; n < 8; ++n) {
                const int col = w * 128 + n * 16 + l15;
                const float v = o[m][n][j] * inv;
                out1[grow + col] = v;
                out2[grow + col] = v;
            }
        }
    }
}

extern "C" void kernel_launch(void* const* d_in, const int* in_sizes, int n_in,
                              void* d_out, int out_size, void* d_ws, size_t ws_size,
                              hipStream_t stream) {
    const float* x  = (const float*)d_in[0];
    const float* Wq = (const float*)d_in[1];
    const float* bq = (const float*)d_in[2];
    const float* Wk = (const float*)d_in[3];
    const float* bk = (const float*)d_in[4];
    const float* Wv = (const float*)d_in[5];
    const float* bv = (const float*)d_in[6];

    float* out   = (float*)d_out;
    float* q_out = out;                                    // [8,2048,1024] f32
    float* out1  = out + (size_t)8 * 2048 * 1024;
    float* out2  = out1 + (size_t)8 * 2048 * 1024;

    short* k_ws  = (short*)d_ws;                           // bf16 [8*4096,1024]
    short* vT_ws = k_ws + (size_t)8 * 4096 * 1024;         // bf16 [8,1024,4096]

    // k = x @ Wk^T + bk  (bf16 -> ws)
    gemm_nt<0><<<dim3(8, 256, 1), 256, 0, stream>>>(x, Wk, bk, (void*)k_ws);
    // vT[b] = Wv @ x_b^T + bv (bf16 -> ws, transposed store for free)
    gemm_nt<1><<<dim3(32, 8, 8), 256, 0, stream>>>(Wv, x, bv, (void*)vT_ws);
    // q = pairmean(x) @ Wq^T + bq (f32 -> output 0)
    gemm_nt<2><<<dim3(8, 128, 1), 256, 0, stream>>>(x, Wq, bq, (void*)q_out);
    // attention -> outputs 1 and 2
    flash_attn<<<dim3(256, 1, 1), 512, 0, stream>>>(q_out, k_ws, vT_ws, out1, out2);
}

// Round 2
// 852.028 us; speedup vs baseline: 1.9543x; 1.9543x over previous
//
#include <hip/hip_runtime.h>
#include <hip/hip_bf16.h>
#include <cstddef>

typedef __attribute__((ext_vector_type(8))) short s16x8;
typedef __attribute__((ext_vector_type(4))) short s16x4;
typedef __attribute__((ext_vector_type(4))) float f32x4;

#define MFMA_BF16(a, b, c) __builtin_amdgcn_mfma_f32_16x16x32_bf16((a), (b), (c), 0, 0, 0)

__device__ __forceinline__ short f2bf(float f) {
    union { float f; unsigned u; } cv; cv.f = f;
    unsigned u = cv.u;
    unsigned r = (u + 0x7FFFu + ((u >> 16) & 1u)) >> 16;  // RNE
    return (short)r;
}
__device__ __forceinline__ float bf2f(unsigned short u) {
    union { unsigned u; float f; } cv; cv.u = ((unsigned)u) << 16; return cv.f;
}

// ---------------------------------------------------------------------------
// NT GEMM, 128x128 tile, BK=64, 4 waves, register-prefetched staging.
// All matmuls here are NT (both operands K-contiguous).
// MODE 0: k   = x @ Wk^T + bk          f32 in  -> bf16 k_ws   [32768,1024]
// MODE 1: vT  = Wv @ x_b^T + bv        f32 in  -> bf16 vT_ws  [8,1024,4096]
// MODE 2: q   = pairmean(x) @ Wq^T+bq  f32 in  -> f32 q_out + bf16 qs (x1/32)
// MODE 3: S   = qs @ k^T               bf16 in -> bf16 S      [8,2048,4096]
// MODE 4: O   = P @ vT^T (K=4096)      bf16 in -> f32 O (x 1/l[row])
// ---------------------------------------------------------------------------
template <int MODE>
__global__ __launch_bounds__(256, 2) void gemm(
    const void* __restrict__ Ap_, const void* __restrict__ Bp_,
    const float* __restrict__ bias, const float* __restrict__ lvec,
    void* __restrict__ Cp, void* __restrict__ Cp2)
{
    constexpr bool F32IN = (MODE <= 2);
    constexpr int NT = (MODE == 4) ? 64 : 16;   // K / 64
    constexpr int LDA = (MODE == 4) ? 4096 : ((MODE == 2) ? 2048 : 1024);
    constexpr int LDB = (MODE == 4) ? 4096 : 1024;

    __shared__ short As[128 * 64];
    __shared__ short Bs[128 * 64];
    const int tid = threadIdx.x;
    const int bx = blockIdx.x, by = blockIdx.y, z = blockIdx.z;
    const int w = tid >> 6, l = tid & 63, l15 = l & 15, lhi = l >> 4;
    const int wy = w >> 1, wx = w & 1;
    const int X = (l15 & 7) << 3;

    // per-mode base pointers (row0 folded in)
    const float* Af = (const float*)Ap_;
    const float* Bf = (const float*)Bp_;
    const short* Ab = (const short*)Ap_;
    const short* Bb = (const short*)Bp_;
    size_t arow0 = (size_t)by * 128, brow0 = (size_t)bx * 128;
    if constexpr (MODE == 1) brow0 += (size_t)z * 4096;
    if constexpr (MODE == 3) { arow0 += (size_t)z * 2048; brow0 += (size_t)z * 4096; }
    if constexpr (MODE == 4) { arow0 += (size_t)z * 2048; brow0 += (size_t)z * 1024; }

    f32x4 acc[4][4];
    #pragma unroll
    for (int m = 0; m < 4; ++m)
        #pragma unroll
        for (int n = 0; n < 4; ++n) acc[m][n] = (f32x4){0.f, 0.f, 0.f, 0.f};

    // staging decomposition
    const int r0f = tid >> 4, kcs = tid & 15;        // f32: 16 rows/round x 8 rounds
    const int r0b = tid >> 3, cb = (tid & 7) * 8;    // bf16: 32 rows/round x 4 rounds

    float4 ra[8], ra2[8], rb[8];
    s16x8 qa[4], qb[4];

    auto load_tile = [&](int kt) {
        if constexpr (F32IN) {
            const int k0 = kt * 64 + kcs * 4;
            #pragma unroll
            for (int p = 0; p < 8; ++p) {
                const int r = r0f + p * 16;
                if constexpr (MODE == 2) {
                    const float* s0 = Af + (arow0 + r) * (size_t)LDA + k0;
                    ra[p] = *(const float4*)s0;
                    ra2[p] = *(const float4*)(s0 + 1024);
                } else {
                    ra[p] = *(const float4*)(Af + (arow0 + r) * (size_t)LDA + k0);
                }
                rb[p] = *(const float4*)(Bf + (brow0 + r) * (size_t)LDB + k0);
            }
        } else {
            const int k0 = kt * 64 + cb;
            #pragma unroll
            for (int p = 0; p < 4; ++p) {
                const int r = r0b + p * 32;
                qa[p] = *(const s16x8*)(Ab + (arow0 + r) * (size_t)LDA + k0);
                qb[p] = *(const s16x8*)(Bb + (brow0 + r) * (size_t)LDB + k0);
            }
        }
    };

    load_tile(0);

    for (int kt = 0; kt < NT; ++kt) {
        // ---- write phase (consumes prefetched regs)
        if constexpr (F32IN) {
            #pragma unroll
            for (int p = 0; p < 8; ++p) {
                const int r = r0f + p * 16;
                const int e = (kcs * 4) ^ ((r & 7) << 3);
                float ax, ay, az, aw;
                if constexpr (MODE == 2) {
                    ax = 0.5f * (ra[p].x + ra2[p].x); ay = 0.5f * (ra[p].y + ra2[p].y);
                    az = 0.5f * (ra[p].z + ra2[p].z); aw = 0.5f * (ra[p].w + ra2[p].w);
                } else {
                    ax = ra[p].x; ay = ra[p].y; az = ra[p].z; aw = ra[p].w;
                }
                s16x4 sa = { f2bf(ax), f2bf(ay), f2bf(az), f2bf(aw) };
                *(s16x4*)&As[r * 64 + e] = sa;
                s16x4 sb = { f2bf(rb[p].x), f2bf(rb[p].y), f2bf(rb[p].z), f2bf(rb[p].w) };
                *(s16x4*)&Bs[r * 64 + e] = sb;
            }
        } else {
            #pragma unroll
            for (int p = 0; p < 4; ++p) {
                const int r = r0b + p * 32;
                const int e = cb ^ ((r & 7) << 3);
                *(s16x8*)&As[r * 64 + e] = qa[p];
                *(s16x8*)&Bs[r * 64 + e] = qb[p];
            }
        }
        // ---- issue next tile's loads (in flight across barrier + MFMA)
        if (kt + 1 < NT) load_tile(kt + 1);
        __syncthreads();
        // ---- MFMA phase
        #pragma unroll
        for (int kk = 0; kk < 2; ++kk) {
            const int e = (kk * 32 + lhi * 8) ^ X;
            s16x8 af[4], bf[4];
            #pragma unroll
            for (int m = 0; m < 4; ++m)
                af[m] = *(const s16x8*)&As[(wy * 64 + m * 16 + l15) * 64 + e];
            #pragma unroll
            for (int n = 0; n < 4; ++n)
                bf[n] = *(const s16x8*)&Bs[(wx * 64 + n * 16 + l15) * 64 + e];
            #pragma unroll
            for (int m = 0; m < 4; ++m)
                #pragma unroll
                for (int n = 0; n < 4; ++n)
                    acc[m][n] = MFMA_BF16(af[m], bf[n], acc[m][n]);
        }
        __syncthreads();
    }

    // ---- epilogue
    #pragma unroll
    for (int m = 0; m < 4; ++m) {
        #pragma unroll
        for (int j = 0; j < 4; ++j) {
            const int rl = wy * 64 + m * 16 + lhi * 4 + j;
            const int grow = by * 128 + rl;
            float radd = 0.f, rmul = 1.f;
            if constexpr (MODE == 1) radd = bias[grow];
            if constexpr (MODE == 4) rmul = 1.0f / lvec[(size_t)z * 2048 + grow];
            #pragma unroll
            for (int n = 0; n < 4; ++n) {
                const int cl = wx * 64 + n * 16 + l15;
                const int gcol = bx * 128 + cl;
                float v = acc[m][n][j];
                if constexpr (MODE == 0) {
                    ((short*)Cp)[(size_t)grow * 1024 + gcol] = f2bf(v + bias[gcol]);
                } else if constexpr (MODE == 1) {
                    ((short*)Cp)[(size_t)z * 4096 * 1024 + (size_t)grow * 4096 + gcol] = f2bf(v + radd);
                } else if constexpr (MODE == 2) {
                    const float q = v + bias[gcol];
                    ((float*)Cp)[(size_t)grow * 1024 + gcol] = q;
                    ((short*)Cp2)[(size_t)grow * 1024 + gcol] = f2bf(q * 0.03125f);
                } else if constexpr (MODE == 3) {
                    ((short*)Cp)[(size_t)z * 2048 * 4096 + (size_t)grow * 4096 + gcol] = f2bf(v);
                } else {
                    ((float*)Cp)[(size_t)z * 2048 * 1024 + (size_t)grow * 1024 + gcol] = v * rmul;
                }
            }
        }
    }
}

// ---------------------------------------------------------------------------
// In-place row softmax over bf16 S [16384 rows x 4096]; writes P (bf16) back
// and row-sum l (fp32). One wave per row.
// ---------------------------------------------------------------------------
__global__ __launch_bounds__(256, 4) void softmax_rows(
    unsigned short* __restrict__ S, float* __restrict__ lvec)
{
    const int w = threadIdx.x >> 6, l = threadIdx.x & 63;
    const int row = blockIdx.x * 4 + w;
    unsigned short* rp = S + (size_t)row * 4096;

    s16x8 v[8];
    #pragma unroll
    for (int c = 0; c < 8; ++c)
        v[c] = *(const s16x8*)(rp + (c * 64 + l) * 8);

    float mx = -1e30f;
    #pragma unroll
    for (int c = 0; c < 8; ++c)
        #pragma unroll
        for (int j = 0; j < 8; ++j)
            mx = fmaxf(mx, bf2f((unsigned short)v[c][j]));
    #pragma unroll
    for (int d = 1; d < 64; d <<= 1) mx = fmaxf(mx, __shfl_xor(mx, d));

    float sum = 0.f;
    #pragma unroll
    for (int c = 0; c < 8; ++c) {
        #pragma unroll
        for (int j = 0; j < 8; ++j) {
            const float p = __expf(bf2f((unsigned short)v[c][j]) - mx);
            sum += p;
            v[c][j] = f2bf(p);
        }
    }
    #pragma unroll
    for (int d = 1; d < 64; d <<= 1) sum += __shfl_xor(sum, d);

    #pragma unroll
    for (int c = 0; c < 8; ++c)
        *(s16x8*)(rp + (c * 64 + l) * 8) = v[c];
    if (l == 0) lvec[row] = sum;
}

// ---------------------------------------------------------------------------
// Duplicate O (f32, ws) into out1 and out2.
// ---------------------------------------------------------------------------
__global__ __launch_bounds__(256, 4) void dup_out(
    const float4* __restrict__ O, float4* __restrict__ o1, float4* __restrict__ o2)
{
    const size_t i0 = (size_t)blockIdx.x * 256 + threadIdx.x;
    #pragma unroll
    for (int p = 0; p < 4; ++p) {
        const size_t i = i0 + (size_t)p * 1048576;
        const float4 t = O[i];
        o1[i] = t;
        o2[i] = t;
    }
}

extern "C" void kernel_launch(void* const* d_in, const int* in_sizes, int n_in,
                              void* d_out, int out_size, void* d_ws, size_t ws_size,
                              hipStream_t stream) {
    const float* x  = (const float*)d_in[0];
    const float* Wq = (const float*)d_in[1];
    const float* bq = (const float*)d_in[2];
    const float* Wk = (const float*)d_in[3];
    const float* bk = (const float*)d_in[4];
    const float* Wv = (const float*)d_in[5];
    const float* bv = (const float*)d_in[6];

    float* out   = (float*)d_out;
    float* q_out = out;                                      // [8,2048,1024] f32
    float* out1  = out + (size_t)16777216;
    float* out2  = out + (size_t)33554432;
    short* Smat  = (short*)out1;                             // bf16 [8,2048,4096] = out1+out2

    short* k_ws  = (short*)d_ws;                             // bf16 [8*4096,1024]
    short* vT_ws = k_ws + (size_t)33554432;                  // bf16 [8,1024,4096]
    short* qs_ws = vT_ws + (size_t)33554432;                 // bf16 [8*2048,1024] (q/32)
    float* l_ws  = (float*)(qs_ws + (size_t)16777216);       // f32 [16384]
    float* O_ws  = (float*)d_ws;                             // f32 [8,2048,1024] aliases k_ws (dead by then)

    // projections
    gemm<0><<<dim3(8, 256, 1), 256, 0, stream>>>(x, Wk, bk, nullptr, (void*)k_ws, nullptr);
    gemm<1><<<dim3(32, 8, 8), 256, 0, stream>>>(Wv, x, bv, nullptr, (void*)vT_ws, nullptr);
    gemm<2><<<dim3(8, 128, 1), 256, 0, stream>>>(x, Wq, bq, nullptr, (void*)q_out, (void*)qs_ws);
    // S = qs @ k^T  (scale already folded into qs)
    gemm<3><<<dim3(32, 16, 8), 256, 0, stream>>>(qs_ws, k_ws, nullptr, nullptr, (void*)Smat, nullptr);
    // P = softmax(S) in place, l = row sums
    softmax_rows<<<dim3(4096, 1, 1), 256, 0, stream>>>((unsigned short*)Smat, l_ws);
    // O = P @ vT^T, normalized by 1/l
    gemm<4><<<dim3(8, 16, 8), 256, 0, stream>>>(Smat, vT_ws, nullptr, l_ws, (void*)O_ws, nullptr);
    // out1 = out2 = O
    dup_out<<<dim3(4096, 1, 1), 256, 0, stream>>>((const float4*)O_ws, (float4*)out1, (float4*)out2);
}

// Round 3
// 758.263 us; speedup vs baseline: 2.1960x; 1.1237x over previous
//
#include <hip/hip_runtime.h>
#include <hip/hip_bf16.h>
#include <cstddef>

typedef __attribute__((ext_vector_type(8))) short s16x8;
typedef __attribute__((ext_vector_type(4))) short s16x4;
typedef __attribute__((ext_vector_type(4))) float f32x4;

#define MFMA_BF16(a, b, c) __builtin_amdgcn_mfma_f32_16x16x32_bf16((a), (b), (c), 0, 0, 0)

__device__ __forceinline__ short f2bf(float f) {
    union { float f; unsigned u; } cv; cv.f = f;
    unsigned u = cv.u;
    unsigned r = (u + 0x7FFFu + ((u >> 16) & 1u)) >> 16;  // RNE
    return (short)r;
}
__device__ __forceinline__ float bf2f(unsigned short u) {
    union { unsigned u; float f; } cv; cv.u = ((unsigned)u) << 16; return cv.f;
}

__device__ __forceinline__ void gl16(const void* g, void* l) {
    __builtin_amdgcn_global_load_lds(
        (const __attribute__((address_space(1))) void*)g,
        (__attribute__((address_space(3))) void*)l, 16, 0, 0);
}

// ---------------------------------------------------------------------------
// bf16 NT GEMM, 128x128 tile, BK=64, 4 waves, global_load_lds staging.
// Swizzle: content chunk c (16B units) of local row r lives at chunk c^(r&7).
// gload: linear LDS dest, source chunk = (lane&7)^(lane>>3)  [rule #21].
// MODE 0: k  = xb @ WkbT + bk            -> bf16 k   [32768,1024]
// MODE 1: vT = Wvb @ xbT + bv            -> bf16 vT  [8,1024,4096]
// MODE 2: q  = pairmean(xb) @ WqbT + bq  -> f32 q    [16384,1024] (A reg-staged)
// MODE 3: S  = (q*1/32) @ kT             -> bf16 S   (A f32 reg-staged)
// MODE 4: O  = P @ vTT (K=4096)          -> f32 O * 1/l[row]
// MODE 5: S  = qs @ kT                   -> bf16 S   (plan-B: qs bf16 gload)
// ---------------------------------------------------------------------------
template <int MODE>
__global__ __launch_bounds__(256, 2) void gemm_bf(
    const void* __restrict__ Ap, const short* __restrict__ Bp,
    const float* __restrict__ bias, const float* __restrict__ lvec,
    void* __restrict__ Cp)
{
    constexpr int NT  = (MODE == 4) ? 64 : 16;
    constexpr int LDA = (MODE == 4) ? 4096 : 1024;
    constexpr int LDB = (MODE == 4) ? 4096 : 1024;

    __shared__ short As[128 * 64];
    __shared__ short Bs[128 * 64];
    const int tid = threadIdx.x;
    const int bx = blockIdx.x, by = blockIdx.y, z = blockIdx.z;
    const int w = tid >> 6, l = tid & 63, l15 = l & 15, lhi = l >> 4;
    const int wy = w >> 1, wx = w & 1;
    const int X = (l15 & 7) << 3;
    const int lr8 = l >> 3, cb = l & 7, scb = cb ^ lr8;

    size_t arow0 = (size_t)by * 128, brow0 = (size_t)bx * 128;
    if constexpr (MODE == 3 || MODE == 4 || MODE == 5) arow0 += (size_t)z * 2048;
    if constexpr (MODE == 1 || MODE == 3 || MODE == 5) brow0 += (size_t)z * 4096;
    if constexpr (MODE == 4) brow0 += (size_t)z * 1024;

    const short* Ab = (const short*)Ap;
    const float* Af = (const float*)Ap;

    // per-lane pre-swizzled gload source bases
    const short* gA = Ab + (arow0 + w * 32 + lr8) * (size_t)LDA + scb * 8;
    const short* gB = Bp + (brow0 + w * 32 + lr8) * (size_t)LDB + scb * 8;

    f32x4 acc[4][4];
    #pragma unroll
    for (int m = 0; m < 4; ++m)
        #pragma unroll
        for (int n = 0; n < 4; ++n) acc[m][n] = (f32x4){0.f, 0.f, 0.f, 0.f};

    const int r0b = tid >> 3, cb8 = (tid & 7) * 8;   // mode-2 A staging
    const int r0f = tid >> 4, kcs = tid & 15;        // mode-3 A staging

    for (int kt = 0; kt < NT; ++kt) {
        // B side: async global->LDS (4 x 8 rows per wave)
        #pragma unroll
        for (int i = 0; i < 4; ++i)
            gl16(gB + (size_t)(i * 8) * LDB + kt * 64, &Bs[(w * 32 + i * 8) * 64]);
        // A side
        if constexpr (MODE == 2) {
            #pragma unroll
            for (int p = 0; p < 4; ++p) {
                const int r = r0b + p * 32;
                const size_t g = (arow0 + r) * 2048 + kt * 64 + cb8;
                s16x8 u0 = *(const s16x8*)(Ab + g);
                s16x8 u1 = *(const s16x8*)(Ab + g + 1024);
                s16x8 o;
                #pragma unroll
                for (int j = 0; j < 8; ++j)
                    o[j] = f2bf(0.5f * (bf2f((unsigned short)u0[j]) + bf2f((unsigned short)u1[j])));
                *(s16x8*)&As[r * 64 + (cb8 ^ ((r & 7) * 8))] = o;
            }
        } else if constexpr (MODE == 3) {
            const int k0 = kt * 64 + kcs * 4;
            #pragma unroll
            for (int p = 0; p < 8; ++p) {
                const int r = r0f + p * 16;
                float4 u = *(const float4*)(Af + (arow0 + r) * 1024 + k0);
                s16x4 sa = { f2bf(u.x * 0.03125f), f2bf(u.y * 0.03125f),
                             f2bf(u.z * 0.03125f), f2bf(u.w * 0.03125f) };
                *(s16x4*)&As[r * 64 + ((kcs * 4) ^ ((r & 7) * 8))] = sa;
            }
        } else {
            #pragma unroll
            for (int i = 0; i < 4; ++i)
                gl16(gA + (size_t)(i * 8) * LDA + kt * 64, &As[(w * 32 + i * 8) * 64]);
        }
        __syncthreads();   // drains vmcnt(0)+lgkmcnt: tile ready
        #pragma unroll
        for (int kk = 0; kk < 2; ++kk) {
            const int e = (kk * 32 + lhi * 8) ^ X;
            s16x8 af[4], bfr[4];
            #pragma unroll
            for (int m = 0; m < 4; ++m)
                af[m] = *(const s16x8*)&As[(wy * 64 + m * 16 + l15) * 64 + e];
            #pragma unroll
            for (int n = 0; n < 4; ++n)
                bfr[n] = *(const s16x8*)&Bs[(wx * 64 + n * 16 + l15) * 64 + e];
            #pragma unroll
            for (int m = 0; m < 4; ++m)
                #pragma unroll
                for (int n = 0; n < 4; ++n)
                    acc[m][n] = MFMA_BF16(af[m], bfr[n], acc[m][n]);
        }
        __syncthreads();   // reads done before next stage overwrites
    }

    #pragma unroll
    for (int m = 0; m < 4; ++m) {
        #pragma unroll
        for (int j = 0; j < 4; ++j) {
            const int rl = wy * 64 + m * 16 + lhi * 4 + j;
            const int grow = by * 128 + rl;
            float radd = 0.f, rmul = 1.f;
            if constexpr (MODE == 1) radd = bias[grow];
            if constexpr (MODE == 4) rmul = 1.0f / lvec[(size_t)z * 2048 + grow];
            #pragma unroll
            for (int n = 0; n < 4; ++n) {
                const int cl = wx * 64 + n * 16 + l15;
                const int gcol = bx * 128 + cl;
                float v = acc[m][n][j];
                if constexpr (MODE == 0) {
                    ((short*)Cp)[(size_t)grow * 1024 + gcol] = f2bf(v + bias[gcol]);
                } else if constexpr (MODE == 1) {
                    ((short*)Cp)[(size_t)z * 4194304 + (size_t)grow * 4096 + gcol] = f2bf(v + radd);
                } else if constexpr (MODE == 2) {
                    ((float*)Cp)[(size_t)grow * 1024 + gcol] = v + bias[gcol];
                } else if constexpr (MODE == 3 || MODE == 5) {
                    ((short*)Cp)[(size_t)z * 8388608 + (size_t)grow * 4096 + gcol] = f2bf(v);
                } else {
                    ((float*)Cp)[(size_t)z * 2097152 + (size_t)grow * 1024 + gcol] = v * rmul;
                }
            }
        }
    }
}

// ---------------------------------------------------------------------------
// Plan-B fallback: f32-input reg-staged GEMM (round-2 proven).
// MODE 0: k = x@WkT+bk -> bf16. MODE 1: vT = Wv@x_bT+bv -> bf16.
// MODE 2: q = pairmean(x)@WqT+bq -> f32 q + bf16 qs (q/32).
// ---------------------------------------------------------------------------
template <int MODE>
__global__ __launch_bounds__(256, 2) void gemm_f32(
    const float* __restrict__ Ap, const float* __restrict__ Bp,
    const float* __restrict__ bias, void* __restrict__ Cp, void* __restrict__ Cp2)
{
    constexpr int LDA = (MODE == 2) ? 2048 : 1024;
    __shared__ short As[128 * 64];
    __shared__ short Bs[128 * 64];
    const int tid = threadIdx.x;
    const int bx = blockIdx.x, by = blockIdx.y, z = blockIdx.z;
    const int w = tid >> 6, l = tid & 63, l15 = l & 15, lhi = l >> 4;
    const int wy = w >> 1, wx = w & 1;
    const int X = (l15 & 7) << 3;

    size_t arow0 = (size_t)by * 128, brow0 = (size_t)bx * 128;
    if constexpr (MODE == 1) brow0 += (size_t)z * 4096;

    f32x4 acc[4][4];
    #pragma unroll
    for (int m = 0; m < 4; ++m)
        #pragma unroll
        for (int n = 0; n < 4; ++n) acc[m][n] = (f32x4){0.f, 0.f, 0.f, 0.f};

    const int r0f = tid >> 4, kcs = tid & 15;
    float4 ra[8], ra2[8], rb[8];

    auto load_tile = [&](int kt) {
        const int k0 = kt * 64 + kcs * 4;
        #pragma unroll
        for (int p = 0; p < 8; ++p) {
            const int r = r0f + p * 16;
            if constexpr (MODE == 2) {
                const float* s0 = Ap + (arow0 + r) * (size_t)LDA + k0;
                ra[p] = *(const float4*)s0;
                ra2[p] = *(const float4*)(s0 + 1024);
            } else {
                ra[p] = *(const float4*)(Ap + (arow0 + r) * (size_t)LDA + k0);
            }
            rb[p] = *(const float4*)(Bp + (brow0 + r) * (size_t)1024 + k0);
        }
    };

    load_tile(0);
    for (int kt = 0; kt < 16; ++kt) {
        #pragma unroll
        for (int p = 0; p < 8; ++p) {
            const int r = r0f + p * 16;
            const int e = (kcs * 4) ^ ((r & 7) << 3);
            float ax, ay, az, aw;
            if constexpr (MODE == 2) {
                ax = 0.5f * (ra[p].x + ra2[p].x); ay = 0.5f * (ra[p].y + ra2[p].y);
                az = 0.5f * (ra[p].z + ra2[p].z); aw = 0.5f * (ra[p].w + ra2[p].w);
            } else {
                ax = ra[p].x; ay = ra[p].y; az = ra[p].z; aw = ra[p].w;
            }
            s16x4 sa = { f2bf(ax), f2bf(ay), f2bf(az), f2bf(aw) };
            *(s16x4*)&As[r * 64 + e] = sa;
            s16x4 sb = { f2bf(rb[p].x), f2bf(rb[p].y), f2bf(rb[p].z), f2bf(rb[p].w) };
            *(s16x4*)&Bs[r * 64 + e] = sb;
        }
        if (kt + 1 < 16) load_tile(kt + 1);
        __syncthreads();
        #pragma unroll
        for (int kk = 0; kk < 2; ++kk) {
            const int e = (kk * 32 + lhi * 8) ^ X;
            s16x8 af[4], bfr[4];
            #pragma unroll
            for (int m = 0; m < 4; ++m)
                af[m] = *(const s16x8*)&As[(wy * 64 + m * 16 + l15) * 64 + e];
            #pragma unroll
            for (int n = 0; n < 4; ++n)
                bfr[n] = *(const s16x8*)&Bs[(wx * 64 + n * 16 + l15) * 64 + e];
            #pragma unroll
            for (int m = 0; m < 4; ++m)
                #pragma unroll
                for (int n = 0; n < 4; ++n)
                    acc[m][n] = MFMA_BF16(af[m], bfr[n], acc[m][n]);
        }
        __syncthreads();
    }

    #pragma unroll
    for (int m = 0; m < 4; ++m) {
        #pragma unroll
        for (int j = 0; j < 4; ++j) {
            const int rl = wy * 64 + m * 16 + lhi * 4 + j;
            const int grow = by * 128 + rl;
            const float radd = (MODE == 1) ? bias[grow] : 0.f;
            #pragma unroll
            for (int n = 0; n < 4; ++n) {
                const int cl = wx * 64 + n * 16 + l15;
                const int gcol = bx * 128 + cl;
                float v = acc[m][n][j];
                if constexpr (MODE == 0) {
                    ((short*)Cp)[(size_t)grow * 1024 + gcol] = f2bf(v + bias[gcol]);
                } else if constexpr (MODE == 1) {
                    ((short*)Cp)[(size_t)z * 4194304 + (size_t)grow * 4096 + gcol] = f2bf(v + radd);
                } else {
                    const float q = v + bias[gcol];
                    ((float*)Cp)[(size_t)grow * 1024 + gcol] = q;
                    ((short*)Cp2)[(size_t)grow * 1024 + gcol] = f2bf(q * 0.03125f);
                }
            }
        }
    }
}

__global__ __launch_bounds__(256, 4) void convert_x(const float* __restrict__ x,
                                                    short* __restrict__ xb)
{
    const size_t i0 = ((size_t)blockIdx.x * 256 + threadIdx.x) * 8;
    float4 a = *(const float4*)(x + i0), b = *(const float4*)(x + i0 + 4);
    s16x8 o = { f2bf(a.x), f2bf(a.y), f2bf(a.z), f2bf(a.w),
                f2bf(b.x), f2bf(b.y), f2bf(b.z), f2bf(b.w) };
    *(s16x8*)(xb + i0) = o;
}

__global__ __launch_bounds__(256, 4) void convert_w(
    const float* __restrict__ Wq, const float* __restrict__ Wk,
    const float* __restrict__ Wv, short* __restrict__ Wb)
{
    const int gid = blockIdx.x * 256 + threadIdx.x;          // 0..393215
    const int seg = gid >> 17;
    const size_t off = (size_t)(gid & 131071) * 8;
    const float* s = (seg == 0) ? Wq : ((seg == 1) ? Wk : Wv);
    float4 a = *(const float4*)(s + off), b = *(const float4*)(s + off + 4);
    s16x8 o = { f2bf(a.x), f2bf(a.y), f2bf(a.z), f2bf(a.w),
                f2bf(b.x), f2bf(b.y), f2bf(b.z), f2bf(b.w) };
    *(s16x8*)(Wb + (size_t)seg * 1048576 + off) = o;
}

__global__ __launch_bounds__(256, 4) void softmax_rows(
    unsigned short* __restrict__ S, float* __restrict__ lvec)
{
    const int w = threadIdx.x >> 6, l = threadIdx.x & 63;
    const int row = blockIdx.x * 4 + w;
    unsigned short* rp = S + (size_t)row * 4096;

    s16x8 v[8];
    #pragma unroll
    for (int c = 0; c < 8; ++c)
        v[c] = *(const s16x8*)(rp + (c * 64 + l) * 8);

    float mx = -1e30f;
    #pragma unroll
    for (int c = 0; c < 8; ++c)
        #pragma unroll
        for (int j = 0; j < 8; ++j)
            mx = fmaxf(mx, bf2f((unsigned short)v[c][j]));
    #pragma unroll
    for (int d = 1; d < 64; d <<= 1) mx = fmaxf(mx, __shfl_xor(mx, d));

    float sum = 0.f;
    #pragma unroll
    for (int c = 0; c < 8; ++c) {
        #pragma unroll
        for (int j = 0; j < 8; ++j) {
            const float p = __expf(bf2f((unsigned short)v[c][j]) - mx);
            sum += p;
            v[c][j] = f2bf(p);
        }
    }
    #pragma unroll
    for (int d = 1; d < 64; d <<= 1) sum += __shfl_xor(sum, d);

    #pragma unroll
    for (int c = 0; c < 8; ++c)
        *(s16x8*)(rp + (c * 64 + l) * 8) = v[c];
    if (l == 0) lvec[row] = sum;
}

__global__ __launch_bounds__(256, 4) void dup_out(
    const float4* __restrict__ O, float4* __restrict__ o1, float4* __restrict__ o2)
{
    const size_t i0 = (size_t)blockIdx.x * 256 + threadIdx.x;
    #pragma unroll
    for (int p = 0; p < 4; ++p) {
        const size_t i = i0 + (size_t)p * 1048576;
        const float4 t = O[i];
        o1[i] = t;
        o2[i] = t;
    }
}

extern "C" void kernel_launch(void* const* d_in, const int* in_sizes, int n_in,
                              void* d_out, int out_size, void* d_ws, size_t ws_size,
                              hipStream_t stream) {
    const float* x  = (const float*)d_in[0];
    const float* Wq = (const float*)d_in[1];
    const float* bq = (const float*)d_in[2];
    const float* Wk = (const float*)d_in[3];
    const float* bk = (const float*)d_in[4];
    const float* Wv = (const float*)d_in[5];
    const float* bv = (const float*)d_in[6];

    float* out   = (float*)d_out;
    float* q_out = out;                                  // [16384,1024] f32
    float* out1  = out + (size_t)16777216;
    float* out2  = out + (size_t)33554432;
    short* Smat  = (short*)out1;                         // bf16 [8,2048,4096]

    const unsigned long long NEED_A = 207683584ULL;      // xb+Wb+k+vT+l

    if ((unsigned long long)ws_size >= NEED_A) {
        // ---- Plan A: all-bf16 pipeline
        short* xb  = (short*)d_ws;                        // [32768,1024]
        short* Wb  = xb + (size_t)33554432;               // [Wqb|Wkb|Wvb]
        short* kws = Wb + (size_t)3145728;                // [32768,1024]
        short* vT  = kws + (size_t)33554432;              // [8,1024,4096]
        float* lws = (float*)((char*)d_ws + 207618048ULL);
        float* Ows = (float*)d_ws;                        // aliases dead xb

        convert_x<<<dim3(16384, 1, 1), 256, 0, stream>>>(x, xb);
        convert_w<<<dim3(1536, 1, 1), 256, 0, stream>>>(Wq, Wk, Wv, Wb);
        gemm_bf<0><<<dim3(8, 256, 1), 256, 0, stream>>>(xb, Wb + 1048576, bk, nullptr, (void*)kws);
        gemm_bf<1><<<dim3(32, 8, 8), 256, 0, stream>>>(Wb + 2097152, xb, bv, nullptr, (void*)vT);
        gemm_bf<2><<<dim3(8, 128, 1), 256, 0, stream>>>(xb, Wb, bq, nullptr, (void*)q_out);
        gemm_bf<3><<<dim3(32, 16, 8), 256, 0, stream>>>(q_out, kws, nullptr, nullptr, (void*)Smat);
        softmax_rows<<<dim3(4096, 1, 1), 256, 0, stream>>>((unsigned short*)Smat, lws);
        gemm_bf<4><<<dim3(8, 16, 8), 256, 0, stream>>>(Smat, vT, nullptr, lws, (void*)Ows);
        dup_out<<<dim3(4096, 1, 1), 256, 0, stream>>>((const float4*)Ows, (float4*)out1, (float4*)out2);
    } else {
        // ---- Plan B: round-2 proven fallback (168 MB ws)
        short* kws = (short*)d_ws;                        // [32768,1024]
        short* vT  = kws + (size_t)33554432;              // [8,1024,4096]
        short* qs  = vT + (size_t)33554432;               // [16384,1024]
        float* lws = (float*)((char*)d_ws + 167772160ULL);
        float* Ows = (float*)d_ws;                        // aliases dead k

        gemm_f32<0><<<dim3(8, 256, 1), 256, 0, stream>>>(x, Wk, bk, (void*)kws, nullptr);
        gemm_f32<1><<<dim3(32, 8, 8), 256, 0, stream>>>(Wv, x, bv, (void*)vT, nullptr);
        gemm_f32<2><<<dim3(8, 128, 1), 256, 0, stream>>>(x, Wq, bq, (void*)q_out, (void*)qs);
        gemm_bf<5><<<dim3(32, 16, 8), 256, 0, stream>>>(qs, kws, nullptr, nullptr, (void*)Smat);
        softmax_rows<<<dim3(4096, 1, 1), 256, 0, stream>>>((unsigned short*)Smat, lws);
        gemm_bf<4><<<dim3(8, 16, 8), 256, 0, stream>>>(Smat, vT, nullptr, lws, (void*)Ows);
        dup_out<<<dim3(4096, 1, 1), 256, 0, stream>>>((const float4*)Ows, (float4*)out1, (float4*)out2);
    }
}

// Round 7
// 652.795 us; speedup vs baseline: 2.5507x; 1.1616x over previous
//
#include <hip/hip_runtime.h>
#include <hip/hip_bf16.h>
#include <cstddef>

typedef __attribute__((ext_vector_type(8))) short s16x8;
typedef __attribute__((ext_vector_type(4))) short s16x4;
typedef __attribute__((ext_vector_type(4))) float f32x4;

#define MFMA_BF16(a, b, c) __builtin_amdgcn_mfma_f32_16x16x32_bf16((a), (b), (c), 0, 0, 0)

__device__ __forceinline__ short f2bf(float f) {
    union { float f; unsigned u; } cv; cv.f = f;
    unsigned u = cv.u;
    unsigned r = (u + 0x7FFFu + ((u >> 16) & 1u)) >> 16;  // RNE
    return (short)r;
}
__device__ __forceinline__ float bf2f(unsigned short u) {
    union { unsigned u; float f; } cv; cv.u = ((unsigned)u) << 16; return cv.f;
}

__device__ __forceinline__ void gl16(const void* g, void* l) {
    __builtin_amdgcn_global_load_lds(
        (const __attribute__((address_space(1))) void*)g,
        (__attribute__((address_space(3))) void*)l, 16, 0, 0);
}

// ---------------------------------------------------------------------------
// bf16 NT GEMM, 128x128 tile, BK=64, 4 waves, global_load_lds staging.
// Swizzle: content chunk c (16B units) of local row r lives at chunk c^(r&7).
// gload: linear LDS dest, source chunk = (lane&7)^(lane>>3)  [rule #21].
// Modes 1,3,4,5 use 1-D grid + XCD batch-affinity decode (z = n&7).
// MODE 0: k  = xb @ WkbT + bk            -> bf16 k   [32768,1024]
// MODE 1: vT = Wvb @ xbT + bv            -> bf16 vT  [8,1024,4096]
// MODE 2: q  = pairmean(xb) @ WqbT + bq  -> f32 q (+ bf16 qs if Cp2)
// MODE 3: S  = (q*1/32) @ kT             -> bf16 S   (A f32 reg-staged, A1 path)
// MODE 4: O  = P @ vTT (K=4096)          -> f32 * 1/l[row] -> Cp AND Cp2
// MODE 5: S  = qs @ kT                   -> bf16 S   (pure gload)
// ---------------------------------------------------------------------------
template <int MODE>
__global__ __launch_bounds__(256, 2) void gemm_bf(
    const void* __restrict__ Ap, const short* __restrict__ Bp,
    const float* __restrict__ bias, const float* __restrict__ lvec,
    void* __restrict__ Cp, void* __restrict__ Cp2)
{
    constexpr int NT  = (MODE == 4) ? 64 : 16;
    constexpr int LDA = (MODE == 4) ? 4096 : 1024;
    constexpr int LDB = (MODE == 4) ? 4096 : 1024;

    __shared__ short As[128 * 64];
    __shared__ short Bs[128 * 64];
    const int tid = threadIdx.x;

    int bx, by, z;
    if constexpr (MODE == 1 || MODE == 3 || MODE == 4 || MODE == 5) {
        const int n = blockIdx.x;
        constexpr int NBY = (MODE == 1) ? 8 : 16;
        z = n & 7; const int m = n >> 3; by = m % NBY; bx = m / NBY;
    } else { bx = blockIdx.x; by = blockIdx.y; z = blockIdx.z; }

    const int w = tid >> 6, l = tid & 63, l15 = l & 15, lhi = l >> 4;
    const int wy = w >> 1, wx = w & 1;
    const int X = (l15 & 7) << 3;
    const int lr8 = l >> 3, cb = l & 7, scb = cb ^ lr8;

    size_t arow0 = (size_t)by * 128, brow0 = (size_t)bx * 128;
    if constexpr (MODE == 3 || MODE == 4 || MODE == 5) arow0 += (size_t)z * 2048;
    if constexpr (MODE == 1 || MODE == 3 || MODE == 5) brow0 += (size_t)z * 4096;
    if constexpr (MODE == 4) brow0 += (size_t)z * 1024;

    const short* Ab = (const short*)Ap;
    const float* Af = (const float*)Ap;

    const short* gA = Ab + (arow0 + w * 32 + lr8) * (size_t)LDA + scb * 8;
    const short* gB = Bp + (brow0 + w * 32 + lr8) * (size_t)LDB + scb * 8;

    f32x4 acc[4][4];
    #pragma unroll
    for (int m = 0; m < 4; ++m)
        #pragma unroll
        for (int n = 0; n < 4; ++n) acc[m][n] = (f32x4){0.f, 0.f, 0.f, 0.f};

    const int r0b = tid >> 3, cb8 = (tid & 7) * 8;   // mode-2 A staging
    const int r0f = tid >> 4, kcs = tid & 15;        // mode-3 A staging

    for (int kt = 0; kt < NT; ++kt) {
        #pragma unroll
        for (int i = 0; i < 4; ++i)
            gl16(gB + (size_t)(i * 8) * LDB + kt * 64, &Bs[(w * 32 + i * 8) * 64]);
        if constexpr (MODE == 2) {
            #pragma unroll
            for (int p = 0; p < 4; ++p) {
                const int r = r0b + p * 32;
                const size_t g = (arow0 + r) * 2048 + kt * 64 + cb8;
                s16x8 u0 = *(const s16x8*)(Ab + g);
                s16x8 u1 = *(const s16x8*)(Ab + g + 1024);
                s16x8 o;
                #pragma unroll
                for (int j = 0; j < 8; ++j)
                    o[j] = f2bf(0.5f * (bf2f((unsigned short)u0[j]) + bf2f((unsigned short)u1[j])));
                *(s16x8*)&As[r * 64 + (cb8 ^ ((r & 7) * 8))] = o;
            }
        } else if constexpr (MODE == 3) {
            const int k0 = kt * 64 + kcs * 4;
            #pragma unroll
            for (int p = 0; p < 8; ++p) {
                const int r = r0f + p * 16;
                float4 u = *(const float4*)(Af + (arow0 + r) * 1024 + k0);
                s16x4 sa = { f2bf(u.x * 0.03125f), f2bf(u.y * 0.03125f),
                             f2bf(u.z * 0.03125f), f2bf(u.w * 0.03125f) };
                *(s16x4*)&As[r * 64 + ((kcs * 4) ^ ((r & 7) * 8))] = sa;
            }
        } else {
            #pragma unroll
            for (int i = 0; i < 4; ++i)
                gl16(gA + (size_t)(i * 8) * LDA + kt * 64, &As[(w * 32 + i * 8) * 64]);
        }
        __syncthreads();
        #pragma unroll
        for (int kk = 0; kk < 2; ++kk) {
            const int e = (kk * 32 + lhi * 8) ^ X;
            s16x8 af[4], bfr[4];
            #pragma unroll
            for (int m = 0; m < 4; ++m)
                af[m] = *(const s16x8*)&As[(wy * 64 + m * 16 + l15) * 64 + e];
            #pragma unroll
            for (int n = 0; n < 4; ++n)
                bfr[n] = *(const s16x8*)&Bs[(wx * 64 + n * 16 + l15) * 64 + e];
            #pragma unroll
            for (int m = 0; m < 4; ++m)
                #pragma unroll
                for (int n = 0; n < 4; ++n)
                    acc[m][n] = MFMA_BF16(af[m], bfr[n], acc[m][n]);
        }
        __syncthreads();
    }

    #pragma unroll
    for (int m = 0; m < 4; ++m) {
        #pragma unroll
        for (int j = 0; j < 4; ++j) {
            const int rl = wy * 64 + m * 16 + lhi * 4 + j;
            const int grow = by * 128 + rl;
            float radd = 0.f, rmul = 1.f;
            if constexpr (MODE == 1) radd = bias[grow];
            if constexpr (MODE == 4) rmul = 1.0f / lvec[(size_t)z * 2048 + grow];
            #pragma unroll
            for (int n = 0; n < 4; ++n) {
                const int cl = wx * 64 + n * 16 + l15;
                const int gcol = bx * 128 + cl;
                float v = acc[m][n][j];
                if constexpr (MODE == 0) {
                    ((short*)Cp)[(size_t)grow * 1024 + gcol] = f2bf(v + bias[gcol]);
                } else if constexpr (MODE == 1) {
                    ((short*)Cp)[(size_t)z * 4194304 + (size_t)grow * 4096 + gcol] = f2bf(v + radd);
                } else if constexpr (MODE == 2) {
                    const float qv = v + bias[gcol];
                    ((float*)Cp)[(size_t)grow * 1024 + gcol] = qv;
                    if (Cp2 != nullptr)
                        ((short*)Cp2)[(size_t)grow * 1024 + gcol] = f2bf(qv * 0.03125f);
                } else if constexpr (MODE == 3 || MODE == 5) {
                    ((short*)Cp)[(size_t)z * 8388608 + (size_t)grow * 4096 + gcol] = f2bf(v);
                } else {
                    const size_t o = ((size_t)z * 2048 + grow) * 1024 + gcol;
                    const float ov = v * rmul;
                    ((float*)Cp)[o] = ov;
                    ((float*)Cp2)[o] = ov;
                }
            }
        }
    }
}

// ---------------------------------------------------------------------------
// Plan-B fallback: f32-input reg-staged GEMM (round-2 proven).
// ---------------------------------------------------------------------------
template <int MODE>
__global__ __launch_bounds__(256, 2) void gemm_f32(
    const float* __restrict__ Ap, const float* __restrict__ Bp,
    const float* __restrict__ bias, void* __restrict__ Cp, void* __restrict__ Cp2)
{
    constexpr int LDA = (MODE == 2) ? 2048 : 1024;
    __shared__ short As[128 * 64];
    __shared__ short Bs[128 * 64];
    const int tid = threadIdx.x;
    const int bx = blockIdx.x, by = blockIdx.y, z = blockIdx.z;
    const int w = tid >> 6, l = tid & 63, l15 = l & 15, lhi = l >> 4;
    const int wy = w >> 1, wx = w & 1;
    const int X = (l15 & 7) << 3;

    size_t arow0 = (size_t)by * 128, brow0 = (size_t)bx * 128;
    if constexpr (MODE == 1) brow0 += (size_t)z * 4096;

    f32x4 acc[4][4];
    #pragma unroll
    for (int m = 0; m < 4; ++m)
        #pragma unroll
        for (int n = 0; n < 4; ++n) acc[m][n] = (f32x4){0.f, 0.f, 0.f, 0.f};

    const int r0f = tid >> 4, kcs = tid & 15;
    float4 ra[8], ra2[8], rb[8];

    auto load_tile = [&](int kt) {
        const int k0 = kt * 64 + kcs * 4;
        #pragma unroll
        for (int p = 0; p < 8; ++p) {
            const int r = r0f + p * 16;
            if constexpr (MODE == 2) {
                const float* s0 = Ap + (arow0 + r) * (size_t)LDA + k0;
                ra[p] = *(const float4*)s0;
                ra2[p] = *(const float4*)(s0 + 1024);
            } else {
                ra[p] = *(const float4*)(Ap + (arow0 + r) * (size_t)LDA + k0);
            }
            rb[p] = *(const float4*)(Bp + (brow0 + r) * (size_t)1024 + k0);
        }
    };

    load_tile(0);
    for (int kt = 0; kt < 16; ++kt) {
        #pragma unroll
        for (int p = 0; p < 8; ++p) {
            const int r = r0f + p * 16;
            const int e = (kcs * 4) ^ ((r & 7) << 3);
            float ax, ay, az, aw;
            if constexpr (MODE == 2) {
                ax = 0.5f * (ra[p].x + ra2[p].x); ay = 0.5f * (ra[p].y + ra2[p].y);
                az = 0.5f * (ra[p].z + ra2[p].z); aw = 0.5f * (ra[p].w + ra2[p].w);
            } else {
                ax = ra[p].x; ay = ra[p].y; az = ra[p].z; aw = ra[p].w;
            }
            s16x4 sa = { f2bf(ax), f2bf(ay), f2bf(az), f2bf(aw) };
            *(s16x4*)&As[r * 64 + e] = sa;
            s16x4 sb = { f2bf(rb[p].x), f2bf(rb[p].y), f2bf(rb[p].z), f2bf(rb[p].w) };
            *(s16x4*)&Bs[r * 64 + e] = sb;
        }
        if (kt + 1 < 16) load_tile(kt + 1);
        __syncthreads();
        #pragma unroll
        for (int kk = 0; kk < 2; ++kk) {
            const int e = (kk * 32 + lhi * 8) ^ X;
            s16x8 af[4], bfr[4];
            #pragma unroll
            for (int m = 0; m < 4; ++m)
                af[m] = *(const s16x8*)&As[(wy * 64 + m * 16 + l15) * 64 + e];
            #pragma unroll
            for (int n = 0; n < 4; ++n)
                bfr[n] = *(const s16x8*)&Bs[(wx * 64 + n * 16 + l15) * 64 + e];
            #pragma unroll
            for (int m = 0; m < 4; ++m)
                #pragma unroll
                for (int n = 0; n < 4; ++n)
                    acc[m][n] = MFMA_BF16(af[m], bfr[n], acc[m][n]);
        }
        __syncthreads();
    }

    #pragma unroll
    for (int m = 0; m < 4; ++m) {
        #pragma unroll
        for (int j = 0; j < 4; ++j) {
            const int rl = wy * 64 + m * 16 + lhi * 4 + j;
            const int grow = by * 128 + rl;
            const float radd = (MODE == 1) ? bias[grow] : 0.f;
            #pragma unroll
            for (int n = 0; n < 4; ++n) {
                const int cl = wx * 64 + n * 16 + l15;
                const int gcol = bx * 128 + cl;
                float v = acc[m][n][j];
                if constexpr (MODE == 0) {
                    ((short*)Cp)[(size_t)grow * 1024 + gcol] = f2bf(v + bias[gcol]);
                } else if constexpr (MODE == 1) {
                    ((short*)Cp)[(size_t)z * 4194304 + (size_t)grow * 4096 + gcol] = f2bf(v + radd);
                } else {
                    const float q = v + bias[gcol];
                    ((float*)Cp)[(size_t)grow * 1024 + gcol] = q;
                    ((short*)Cp2)[(size_t)grow * 1024 + gcol] = f2bf(q * 0.03125f);
                }
            }
        }
    }
}

__global__ __launch_bounds__(256, 4) void convert_x(const float* __restrict__ x,
                                                    short* __restrict__ xb)
{
    const size_t i0 = ((size_t)blockIdx.x * 256 + threadIdx.x) * 8;
    float4 a = *(const float4*)(x + i0), b = *(const float4*)(x + i0 + 4);
    s16x8 o = { f2bf(a.x), f2bf(a.y), f2bf(a.z), f2bf(a.w),
                f2bf(b.x), f2bf(b.y), f2bf(b.z), f2bf(b.w) };
    *(s16x8*)(xb + i0) = o;
}

__global__ __launch_bounds__(256, 4) void convert_w(
    const float* __restrict__ Wq, const float* __restrict__ Wk,
    const float* __restrict__ Wv, short* __restrict__ Wb)
{
    const int gid = blockIdx.x * 256 + threadIdx.x;
    const int seg = gid >> 17;
    const size_t off = (size_t)(gid & 131071) * 8;
    const float* s = (seg == 0) ? Wq : ((seg == 1) ? Wk : Wv);
    float4 a = *(const float4*)(s + off), b = *(const float4*)(s + off + 4);
    s16x8 o = { f2bf(a.x), f2bf(a.y), f2bf(a.z), f2bf(a.w),
                f2bf(b.x), f2bf(b.y), f2bf(b.z), f2bf(b.w) };
    *(s16x8*)(Wb + (size_t)seg * 1048576 + off) = o;
}

__global__ __launch_bounds__(256, 4) void softmax_rows(
    const unsigned short* __restrict__ Sin, unsigned short* __restrict__ Pout,
    float* __restrict__ lvec)
{
    const int w = threadIdx.x >> 6, l = threadIdx.x & 63;
    const int row = blockIdx.x * 4 + w;
    const unsigned short* rp = Sin + (size_t)row * 4096;
    unsigned short* wp = Pout + (size_t)row * 4096;

    s16x8 v[8];
    #pragma unroll
    for (int c = 0; c < 8; ++c)
        v[c] = *(const s16x8*)(rp + (c * 64 + l) * 8);

    float mx = -1e30f;
    #pragma unroll
    for (int c = 0; c < 8; ++c)
        #pragma unroll
        for (int j = 0; j < 8; ++j)
            mx = fmaxf(mx, bf2f((unsigned short)v[c][j]));
    #pragma unroll
    for (int d = 1; d < 64; d <<= 1) mx = fmaxf(mx, __shfl_xor(mx, d));

    float sum = 0.f;
    #pragma unroll
    for (int c = 0; c < 8; ++c) {
        #pragma unroll
        for (int j = 0; j < 8; ++j) {
            const float p = __expf(bf2f((unsigned short)v[c][j]) - mx);
            sum += p;
            v[c][j] = f2bf(p);
        }
    }
    #pragma unroll
    for (int d = 1; d < 64; d <<= 1) sum += __shfl_xor(sum, d);

    #pragma unroll
    for (int c = 0; c < 8; ++c)
        *(s16x8*)(wp + (c * 64 + l) * 8) = v[c];
    if (l == 0) lvec[row] = sum;
}

__global__ __launch_bounds__(256, 4) void dup_out(
    const float4* __restrict__ O, float4* __restrict__ o1, float4* __restrict__ o2)
{
    const size_t i0 = (size_t)blockIdx.x * 256 + threadIdx.x;
    #pragma unroll
    for (int p = 0; p < 4; ++p) {
        const size_t i = i0 + (size_t)p * 1048576;
        const float4 t = O[i];
        o1[i] = t;
        o2[i] = t;
    }
}

extern "C" void kernel_launch(void* const* d_in, const int* in_sizes, int n_in,
                              void* d_out, int out_size, void* d_ws, size_t ws_size,
                              hipStream_t stream) {
    const float* x  = (const float*)d_in[0];
    const float* Wq = (const float*)d_in[1];
    const float* bq = (const float*)d_in[2];
    const float* Wk = (const float*)d_in[3];
    const float* bk = (const float*)d_in[4];
    const float* Wv = (const float*)d_in[5];
    const float* bv = (const float*)d_in[6];

    float* out   = (float*)d_out;
    float* q_out = out;                                  // [16384,1024] f32
    float* out1  = out + (size_t)16777216;
    float* out2  = out + (size_t)33554432;
    short* Smat  = (short*)out1;                         // bf16 [8,2048,4096]

    const unsigned long long NEED_A2 = 241434624ULL;     // xb+Wb+k+vT+qs+l
    const unsigned long long NEED_A1 = 207683584ULL;     // xb+Wb+k+vT+l

    if ((unsigned long long)ws_size >= NEED_A2) {
        // ---- Plan A2: all-bf16, pure-gload S, P in ws, PV dual-write
        short* xb  = (short*)d_ws;                        // [32768,1024]
        short* Wb  = xb + (size_t)33554432;               // [Wqb|Wkb|Wvb]
        short* kws = Wb + (size_t)3145728;                // [32768,1024]
        short* vT  = kws + (size_t)33554432;              // [8,1024,4096]
        short* qs  = vT + (size_t)33554432;               // [16384,1024] (q/32)
        float* lws = (float*)(qs + (size_t)16777216);
        unsigned short* Pws = (unsigned short*)d_ws;      // [16384,4096] aliases dead xb+Wb+k

        convert_x<<<dim3(16384, 1, 1), 256, 0, stream>>>(x, xb);
        convert_w<<<dim3(1536, 1, 1), 256, 0, stream>>>(Wq, Wk, Wv, Wb);
        gemm_bf<0><<<dim3(8, 256, 1), 256, 0, stream>>>(xb, Wb + 1048576, bk, nullptr, (void*)kws, nullptr);
        gemm_bf<1><<<dim3(2048, 1, 1), 256, 0, stream>>>(Wb + 2097152, xb, bv, nullptr, (void*)vT, nullptr);
        gemm_bf<2><<<dim3(8, 128, 1), 256, 0, stream>>>(xb, Wb, bq, nullptr, (void*)q_out, (void*)qs);
        gemm_bf<5><<<dim3(4096, 1, 1), 256, 0, stream>>>(qs, kws, nullptr, nullptr, (void*)Smat, nullptr);
        softmax_rows<<<dim3(4096, 1, 1), 256, 0, stream>>>((const unsigned short*)Smat, Pws, lws);
        gemm_bf<4><<<dim3(1024, 1, 1), 256, 0, stream>>>(Pws, vT, nullptr, lws, (void*)out1, (void*)out2);
    } else if ((unsigned long long)ws_size >= NEED_A1) {
        // ---- Plan A1: round-3 structure + P-in-ws + PV dual-write
        short* xb  = (short*)d_ws;
        short* Wb  = xb + (size_t)33554432;
        short* kws = Wb + (size_t)3145728;
        short* vT  = kws + (size_t)33554432;
        float* lws = (float*)((char*)d_ws + 207618048ULL);
        unsigned short* Pws = (unsigned short*)d_ws;      // aliases dead xb+Wb+k

        convert_x<<<dim3(16384, 1, 1), 256, 0, stream>>>(x, xb);
        convert_w<<<dim3(1536, 1, 1), 256, 0, stream>>>(Wq, Wk, Wv, Wb);
        gemm_bf<0><<<dim3(8, 256, 1), 256, 0, stream>>>(xb, Wb + 1048576, bk, nullptr, (void*)kws, nullptr);
        gemm_bf<1><<<dim3(2048, 1, 1), 256, 0, stream>>>(Wb + 2097152, xb, bv, nullptr, (void*)vT, nullptr);
        gemm_bf<2><<<dim3(8, 128, 1), 256, 0, stream>>>(xb, Wb, bq, nullptr, (void*)q_out, nullptr);
        gemm_bf<3><<<dim3(4096, 1, 1), 256, 0, stream>>>(q_out, kws, nullptr, nullptr, (void*)Smat, nullptr);
        softmax_rows<<<dim3(4096, 1, 1), 256, 0, stream>>>((const unsigned short*)Smat, Pws, lws);
        gemm_bf<4><<<dim3(1024, 1, 1), 256, 0, stream>>>(Pws, vT, nullptr, lws, (void*)out1, (void*)out2);
    } else {
        // ---- Plan B: round-2 proven fallback (168 MB ws)
        short* kws = (short*)d_ws;
        short* vT  = kws + (size_t)33554432;
        short* qs  = vT + (size_t)33554432;
        float* lws = (float*)((char*)d_ws + 167772160ULL);
        float* Ows = (float*)d_ws;                        // aliases dead k

        gemm_f32<0><<<dim3(8, 256, 1), 256, 0, stream>>>(x, Wk, bk, (void*)kws, nullptr);
        gemm_f32<1><<<dim3(32, 8, 8), 256, 0, stream>>>(Wv, x, bv, (void*)vT, nullptr);
        gemm_f32<2><<<dim3(8, 128, 1), 256, 0, stream>>>(x, Wq, bq, (void*)q_out, (void*)qs);
        gemm_bf<5><<<dim3(4096, 1, 1), 256, 0, stream>>>(qs, kws, nullptr, nullptr, (void*)Smat, nullptr);
        softmax_rows<<<dim3(4096, 1, 1), 256, 0, stream>>>((const unsigned short*)Smat, (unsigned short*)Smat, lws);
        gemm_bf<4><<<dim3(1024, 1, 1), 256, 0, stream>>>(Smat, vT, nullptr, lws, (void*)Ows, (void*)Ows);
        dup_out<<<dim3(4096, 1, 1), 256, 0, stream>>>((const float4*)Ows, (float4*)out1, (float4*)out2);
    }
}